// Round 11
// baseline (312.324 us; speedup 1.0000x reference)
//
#include <hip/hip_runtime.h>
#include <cstdint>

#define H 128
#define NGRAPH 256
#define ROWSTRIDE 68   // u32 per LDS tile row (64 data + 4 pad) -> 2-way max bank conflict
#define NPB 128        // nodes per bucket (bucket = dst >> 7)
#define NBMAX 512      // array sizing for bucket counts (NB = ceil(N/128) = 391)
#define CSR_CAP 3072   // LDS staging entries per bucket (mean ~2046, +22 sigma safe)
#define SCHUNK 1024    // edges per scatter block -> 782 blocks (~3/CU)

typedef __attribute__((ext_vector_type(8))) short short8;
typedef __attribute__((ext_vector_type(4))) float floatx4;

typedef unsigned short u16;
typedef unsigned int u32;

__device__ __forceinline__ u16 f2b(float f) {
    union { float f; u32 u; } v; v.f = f;
    u32 r = v.u + 0x7fffu + ((v.u >> 16) & 1u);
    return (u16)(r >> 16);
}
// bare u16 bf16 -> float (ONE shift)
__device__ __forceinline__ float b2f(u16 b) {
    union { u32 u; float f; } v; v.u = ((u32)b) << 16;
    return v.f;
}
// packed-pair helpers: take the full u32 holding two bf16
__device__ __forceinline__ float lo_f(u32 v) {
    union { u32 u; float f; } w; w.u = v << 16; return w.f;
}
__device__ __forceinline__ float hi_f(u32 v) {
    union { u32 u; float f; } w; w.u = v & 0xffff0000u; return w.f;
}

// ------------------------- fp32 -> bf16 convert -------------------------
__global__ void convert_kernel(const float* __restrict__ in, u16* __restrict__ out, int n4) {
    int i = blockIdx.x * blockDim.x + threadIdx.x;
    if (i < n4) {
        float4 v = *(const float4*)(in + (size_t)i * 4);
        u16 o[4] = { f2b(v.x), f2b(v.y), f2b(v.z), f2b(v.w) };
        *(uint2*)(out + (size_t)i * 4) = *(uint2*)o;
    }
}

// ------------------------- pack W into MFMA B-fragment order -------------------------
// packed[mat][ ((kc*8+nt)*64 + lane)*8 + j ] = W[mat][k=kc*32+(lane>>4)*8+j][n=nt*16+(lane&15)]
__global__ void pack_w_kernel(const float* __restrict__ W1, const float* __restrict__ W2,
                              u16* __restrict__ packed, int total) {
    int idx = blockIdx.x * blockDim.x + threadIdx.x;
    if (idx >= total) return;
    int mat = idx >> 14;           // /16384
    int pos = idx & 16383;
    int j    = pos & 7;
    int lane = (pos >> 3) & 63;
    int nt   = (pos >> 9) & 7;
    int kc   = pos >> 12;
    int k = kc * 32 + (lane >> 4) * 8 + j;
    int n = nt * 16 + (lane & 15);
    const float* src = (mat < 3) ? (W1 + (size_t)mat * H * H) : (W2 + (size_t)(mat - 3) * H * H);
    packed[idx] = f2b(src[(size_t)k * H + n]);
}

// ------------------------- CSR build: two-level bucket sort -------------------------
// [R11: CSR kernels were grid-starved (196-256 blocks = <1/CU). hist grid 1024,
//  scatter 782 blocks, build 391 blocks.]
__global__ __launch_bounds__(256) void bucket_hist(const int* __restrict__ dstv,
                                                   int* __restrict__ bcnt, int E, int NB) {
    __shared__ int sh[NBMAX];
    int t = threadIdx.x;
    sh[t] = 0;
    sh[t + 256] = 0;
    __syncthreads();
    for (int e = blockIdx.x * 256 + t; e < E; e += gridDim.x * 256)
        atomicAdd(&sh[dstv[e] >> 7], 1);
    __syncthreads();
    for (int b = t; b < NB; b += 256)
        if (sh[b] > 0) atomicAdd(&bcnt[b], sh[b]);
}

__global__ void bucket_scan(const int* __restrict__ bcnt, int* __restrict__ boffs,
                            int* __restrict__ bcursor, int NB) {
    if (threadIdx.x == 0 && blockIdx.x == 0) {
        int run = 0;
        for (int i = 0; i < NB; ++i) { boffs[i] = run; bcursor[i] = run; run += bcnt[i]; }
        boffs[NB] = run;
    }
}

__global__ __launch_bounds__(256) void scatter_kernel(const int* __restrict__ src,
                                                      const int* __restrict__ dstv,
                                                      int* __restrict__ bcursor,
                                                      u32* __restrict__ stage, int E, int NB) {
    __shared__ int lcnt[NBMAX];
    __shared__ int lbase[NBMAX];
    int t = threadIdx.x;
    lcnt[t] = 0;
    lcnt[t + 256] = 0;
    __syncthreads();
    int base = blockIdx.x * SCHUNK;
    u32 pk[4];
    int bk[4];
#pragma unroll
    for (int i = 0; i < 4; ++i) {
        int idx = base + t + i * 256;
        bk[i] = -1;
        if (idx < E) {
            int s = src[idx];
            int d = dstv[idx];
            int b = d >> 7;
            pk[i] = (u32)s | ((u32)(d & 127) << 24);   // src < 2^24
            bk[i] = b;
            atomicAdd(&lcnt[b], 1);
        }
    }
    __syncthreads();
    for (int b = t; b < NB; b += 256)
        if (lcnt[b] > 0) lbase[b] = atomicAdd(&bcursor[b], lcnt[b]);
    __syncthreads();
    lcnt[t] = 0;
    lcnt[t + 256] = 0;
    __syncthreads();
#pragma unroll
    for (int i = 0; i < 4; ++i) {
        if (bk[i] >= 0) {
            int r = atomicAdd(&lcnt[bk[i]], 1);
            stage[(size_t)lbase[bk[i]] + r] = pk[i];
        }
    }
}

// One block per 128-node bucket: per-node count -> LDS scan -> offs -> LDS col scatter
// -> linear write-out.
__global__ __launch_bounds__(256) void build_csr(const u32* __restrict__ stage,
                                                 const int* __restrict__ boffs,
                                                 int* __restrict__ offs, int* __restrict__ cols,
                                                 int N, int NB, int E) {
    __shared__ int cnt[NPB];
    __shared__ int cur[NPB];
    __shared__ int sA[NPB];
    __shared__ int sB[NPB];
    __shared__ int colstage[CSR_CAP];
    int b = blockIdx.x;
    int t = threadIdx.x;
    int lo = boffs[b], hi = boffs[b + 1];
    int sz = hi - lo;
    int nlo = b * NPB;
    if (t < NPB) cnt[t] = 0;
    __syncthreads();
    for (int i = t; i < sz; i += 256) atomicAdd(&cnt[stage[(size_t)lo + i] >> 24], 1);
    __syncthreads();
    if (t < NPB) sA[t] = cnt[t];
    __syncthreads();
    int* a = sA; int* bb = sB;
    for (int off = 1; off < NPB; off <<= 1) {
        if (t < NPB) bb[t] = (t >= off) ? (a[t] + a[t - off]) : a[t];
        __syncthreads();
        int* tmp = a; a = bb; bb = tmp;
    }
    if (t < NPB) {
        int excl = a[t] - cnt[t];
        if (nlo + t < N) offs[nlo + t] = lo + excl;
        cur[t] = excl;
    }
    if (b == 0 && t == 0) offs[N] = E;
    __syncthreads();
    if (sz <= CSR_CAP) {
        for (int i = t; i < sz; i += 256) {
            u32 pk = stage[(size_t)lo + i];
            int r = atomicAdd(&cur[pk >> 24], 1);
            colstage[r] = (int)(pk & 0xFFFFFFu);
        }
        __syncthreads();
        for (int i = t; i < sz; i += 256) cols[(size_t)lo + i] = colstage[i];
    } else {
        for (int i = t; i < sz; i += 256) {
            u32 pk = stage[(size_t)lo + i];
            int r = atomicAdd(&cur[pk >> 24], 1);
            cols[(size_t)lo + r] = (int)(pk & 0xFFFFFFu);
        }
    }
}

// ------------------------- fused GIN layer -------------------------
// One block per 16-node tile: gather (CSR) -> LDS -> MFMA GEMM1(+bias,ReLU) -> LDS ->
// MFMA GEMM2(+bias,opt ReLU) -> store (or, last layer, fused dot with Wh -> y).
// Gather: GROUP-PARALLEL (16-lane group per node, 4 nodes/wave in parallel); each lane
// reads 16 contiguous bytes of the row with ONE global_load_dwordx4, unrolled x8.
// [R8 lesson: wave-sequential gather regressed — MLP > exec-mask.]
// [R10 lesson: dword->dwordx4 was neutral — gather is NOT issue-bound; it sits at the
//  L2/L3 random-access throughput/occupancy plateau. Don't polish this further.]
__global__ __launch_bounds__(256) void fused_layer(const u16* __restrict__ h,
                                                   u16* __restrict__ hout,
                                                   const int* __restrict__ offs,
                                                   const int* __restrict__ cols,
                                                   const u16* __restrict__ Wp1,
                                                   const u16* __restrict__ Wp2,
                                                   const float* __restrict__ bias1,
                                                   const float* __restrict__ bias2,
                                                   const float* __restrict__ eps, int layer,
                                                   int relu2, int lastLayer,
                                                   const float* __restrict__ Wh,
                                                   float* __restrict__ y, int N) {
    __shared__ u32 ldsA[16 * ROWSTRIDE];
    __shared__ u32 ldsB[16 * ROWSTRIDE];
    __shared__ float dacc[16];

    const int tid = threadIdx.x;
    const int wave = tid >> 6;
    const int lane = tid & 63;
    const int m = lane & 15;
    const int quad = lane >> 4;
    const int nt0 = wave * 2, nt1 = wave * 2 + 1;
    const int row0 = blockIdx.x * 16;

    const float scale = 1.0f + eps[layer];
    const uint4* __restrict__ hp4 = (const uint4*)h;   // row = 16 uint4 (256 B)

    // ---- gather: lane covers 16 contiguous B (8 feats) of its group's node row ----
    {
        const int nid = wave * 4 + quad;       // 0..15
        const int node = row0 + nid;
        float a[8];
#pragma unroll
        for (int i = 0; i < 8; ++i) a[i] = 0.f;
        if (node < N) {
            uint4 sv = hp4[(size_t)node * 16 + m];
            a[0] = scale * lo_f(sv.x); a[1] = scale * hi_f(sv.x);
            a[2] = scale * lo_f(sv.y); a[3] = scale * hi_f(sv.y);
            a[4] = scale * lo_f(sv.z); a[5] = scale * hi_f(sv.z);
            a[6] = scale * lo_f(sv.w); a[7] = scale * hi_f(sv.w);
            int beg = offs[node], end = offs[node + 1];
            int j = beg;
            for (; j + 8 <= end; j += 8) {
                int c[8];
#pragma unroll
                for (int r = 0; r < 8; ++r) c[r] = cols[j + r];
                uint4 v[8];
#pragma unroll
                for (int r = 0; r < 8; ++r) v[r] = hp4[(size_t)c[r] * 16 + m];
#pragma unroll
                for (int r = 0; r < 8; ++r) {
                    a[0] += lo_f(v[r].x); a[1] += hi_f(v[r].x);
                    a[2] += lo_f(v[r].y); a[3] += hi_f(v[r].y);
                    a[4] += lo_f(v[r].z); a[5] += hi_f(v[r].z);
                    a[6] += lo_f(v[r].w); a[7] += hi_f(v[r].w);
                }
            }
            for (; j < end; ++j) {
                uint4 v = hp4[(size_t)cols[j] * 16 + m];
                a[0] += lo_f(v.x); a[1] += hi_f(v.x);
                a[2] += lo_f(v.y); a[3] += hi_f(v.y);
                a[4] += lo_f(v.z); a[5] += hi_f(v.z);
                a[6] += lo_f(v.w); a[7] += hi_f(v.w);
            }
        }
        u16 p[8] = { f2b(a[0]), f2b(a[1]), f2b(a[2]), f2b(a[3]),
                     f2b(a[4]), f2b(a[5]), f2b(a[6]), f2b(a[7]) };
        *(uint4*)(&ldsA[nid * ROWSTRIDE + m * 4]) = *(uint4*)p;   // 16B-aligned ds_write_b128
    }

    // B fragments (loaded in the gather's latency shadow)
    short8 B1f0[4], B1f1[4], B2f0[4], B2f1[4];
#pragma unroll
    for (int kc = 0; kc < 4; ++kc) {
        B1f0[kc] = *(const short8*)(Wp1 + ((size_t)(kc * 8 + nt0) * 64 + lane) * 8);
        B1f1[kc] = *(const short8*)(Wp1 + ((size_t)(kc * 8 + nt1) * 64 + lane) * 8);
        B2f0[kc] = *(const short8*)(Wp2 + ((size_t)(kc * 8 + nt0) * 64 + lane) * 8);
        B2f1[kc] = *(const short8*)(Wp2 + ((size_t)(kc * 8 + nt1) * 64 + lane) * 8);
    }
    const int cg0 = nt0 * 16 + m, cg1 = nt1 * 16 + m;
    const float b1v0 = bias1[cg0], b1v1 = bias1[cg1];
    const float b2v0 = bias2[cg0], b2v1 = bias2[cg1];
    __syncthreads();

    // ---- GEMM1: z1 = relu(z0 @ W1 + b1) ----
    {
        short8 a0 = *(const short8*)(&ldsA[m * ROWSTRIDE + 0 * 16 + quad * 4]);
        short8 a1 = *(const short8*)(&ldsA[m * ROWSTRIDE + 1 * 16 + quad * 4]);
        short8 a2 = *(const short8*)(&ldsA[m * ROWSTRIDE + 2 * 16 + quad * 4]);
        short8 a3 = *(const short8*)(&ldsA[m * ROWSTRIDE + 3 * 16 + quad * 4]);
        floatx4 acc0 = {0.f, 0.f, 0.f, 0.f};
        floatx4 acc1 = {0.f, 0.f, 0.f, 0.f};
        acc0 = __builtin_amdgcn_mfma_f32_16x16x32_bf16(a0, B1f0[0], acc0, 0, 0, 0);
        acc1 = __builtin_amdgcn_mfma_f32_16x16x32_bf16(a0, B1f1[0], acc1, 0, 0, 0);
        acc0 = __builtin_amdgcn_mfma_f32_16x16x32_bf16(a1, B1f0[1], acc0, 0, 0, 0);
        acc1 = __builtin_amdgcn_mfma_f32_16x16x32_bf16(a1, B1f1[1], acc1, 0, 0, 0);
        acc0 = __builtin_amdgcn_mfma_f32_16x16x32_bf16(a2, B1f0[2], acc0, 0, 0, 0);
        acc1 = __builtin_amdgcn_mfma_f32_16x16x32_bf16(a2, B1f1[2], acc1, 0, 0, 0);
        acc0 = __builtin_amdgcn_mfma_f32_16x16x32_bf16(a3, B1f0[3], acc0, 0, 0, 0);
        acc1 = __builtin_amdgcn_mfma_f32_16x16x32_bf16(a3, B1f1[3], acc1, 0, 0, 0);
        u16* lb = (u16*)ldsB;
#pragma unroll
        for (int i = 0; i < 4; ++i) {
            int rr = quad * 4 + i;
            lb[rr * (ROWSTRIDE * 2) + cg0] = f2b(fmaxf(acc0[i] + b1v0, 0.f));
            lb[rr * (ROWSTRIDE * 2) + cg1] = f2b(fmaxf(acc1[i] + b1v1, 0.f));
        }
        if (tid < 16) dacc[tid] = 0.f;
    }
    __syncthreads();

    // ---- GEMM2: z2 = (relu?)(z1 @ W2 + b2) ----
    {
        short8 a0 = *(const short8*)(&ldsB[m * ROWSTRIDE + 0 * 16 + quad * 4]);
        short8 a1 = *(const short8*)(&ldsB[m * ROWSTRIDE + 1 * 16 + quad * 4]);
        short8 a2 = *(const short8*)(&ldsB[m * ROWSTRIDE + 2 * 16 + quad * 4]);
        short8 a3 = *(const short8*)(&ldsB[m * ROWSTRIDE + 3 * 16 + quad * 4]);
        floatx4 acc0 = {0.f, 0.f, 0.f, 0.f};
        floatx4 acc1 = {0.f, 0.f, 0.f, 0.f};
        acc0 = __builtin_amdgcn_mfma_f32_16x16x32_bf16(a0, B2f0[0], acc0, 0, 0, 0);
        acc1 = __builtin_amdgcn_mfma_f32_16x16x32_bf16(a0, B2f1[0], acc1, 0, 0, 0);
        acc0 = __builtin_amdgcn_mfma_f32_16x16x32_bf16(a1, B2f0[1], acc0, 0, 0, 0);
        acc1 = __builtin_amdgcn_mfma_f32_16x16x32_bf16(a1, B2f1[1], acc1, 0, 0, 0);
        acc0 = __builtin_amdgcn_mfma_f32_16x16x32_bf16(a2, B2f0[2], acc0, 0, 0, 0);
        acc1 = __builtin_amdgcn_mfma_f32_16x16x32_bf16(a2, B2f1[2], acc1, 0, 0, 0);
        acc0 = __builtin_amdgcn_mfma_f32_16x16x32_bf16(a3, B2f0[3], acc0, 0, 0, 0);
        acc1 = __builtin_amdgcn_mfma_f32_16x16x32_bf16(a3, B2f1[3], acc1, 0, 0, 0);

        if (!lastLayer) {
            u16* la = (u16*)ldsA;
#pragma unroll
            for (int i = 0; i < 4; ++i) {
                int rr = quad * 4 + i;
                float v0 = acc0[i] + b2v0;
                float v1 = acc1[i] + b2v1;
                if (relu2) { v0 = fmaxf(v0, 0.f); v1 = fmaxf(v1, 0.f); }
                la[rr * (ROWSTRIDE * 2) + cg0] = f2b(v0);
                la[rr * (ROWSTRIDE * 2) + cg1] = f2b(v1);
            }
            __syncthreads();
            // coalesced store: each thread copies 16B
            int rr = tid >> 4;
            int s  = tid & 15;
            int grow = row0 + rr;
            if (grow < N) {
                uint4 v = *(uint4*)(&ldsA[rr * ROWSTRIDE + s * 4]);
                *(uint4*)(hout + (size_t)grow * H + s * 8) = v;
            }
        } else {
            // fused head: y[row] = sum_c bf16(z2[row][c]) * Wh[c]
            const float wh0 = Wh[cg0], wh1 = Wh[cg1];
            float part[4];
#pragma unroll
            for (int i = 0; i < 4; ++i)
                part[i] = b2f(f2b(acc0[i] + b2v0)) * wh0 +
                          b2f(f2b(acc1[i] + b2v1)) * wh1;
            // reduce across the 16 lanes of each quad group (xor masks < 16 stay in-group)
#pragma unroll
            for (int off = 1; off < 16; off <<= 1)
#pragma unroll
                for (int i = 0; i < 4; ++i) part[i] += __shfl_xor(part[i], off, 64);
            if (m == 0) {
#pragma unroll
                for (int i = 0; i < 4; ++i) atomicAdd(&dacc[quad * 4 + i], part[i]);
            }
            __syncthreads();
            if (tid < 16 && row0 + tid < N) y[row0 + tid] = dacc[tid];
        }
    }
}

// ------------------------- per-graph mean via binary search on sorted batch -------------------------
__device__ __forceinline__ int lbound(const int* __restrict__ a, int n, int v) {
    int lo = 0, hi = n;
    while (lo < hi) { int mid = (lo + hi) >> 1; if (a[mid] < v) lo = mid + 1; else hi = mid; }
    return lo;
}

__global__ void seg_out_kernel(const float* __restrict__ y, const int* __restrict__ batch,
                               const float* __restrict__ bh, float* __restrict__ out, int N) {
    __shared__ float sh[256];
    int g = blockIdx.x;
    int lo = lbound(batch, N, g);
    int hi = lbound(batch, N, g + 1);
    float s = 0.f;
    for (int i = lo + threadIdx.x; i < hi; i += 256) s += y[i];
    sh[threadIdx.x] = s;
    __syncthreads();
    for (int off = 128; off > 0; off >>= 1) {
        if (threadIdx.x < off) sh[threadIdx.x] += sh[threadIdx.x + off];
        __syncthreads();
    }
    if (threadIdx.x == 0) {
        float cnt = (float)(hi - lo);
        out[g] = sh[0] / fmaxf(cnt, 1.0f) + bh[0];
    }
}

// ------------------------- launch -------------------------
extern "C" void kernel_launch(void* const* d_in, const int* in_sizes, int n_in,
                              void* d_out, int out_size, void* d_ws, size_t ws_size,
                              hipStream_t stream) {
    const float* x    = (const float*)d_in[0];
    const int*   eidx = (const int*)d_in[1];
    const int*   batch= (const int*)d_in[2];
    const float* W1   = (const float*)d_in[3];
    const float* b1   = (const float*)d_in[4];
    const float* W2   = (const float*)d_in[5];
    const float* b2   = (const float*)d_in[6];
    const float* eps  = (const float*)d_in[7];
    const float* Wh   = (const float*)d_in[8];
    const float* bh   = (const float*)d_in[9];

    const int N = in_sizes[0] / H;   // 50000
    const int E = in_sizes[1] / 2;   // 800000
    const int L = in_sizes[7];       // 3
    const int* src  = eidx;
    const int* dstv = eidx + E;
    float* out = (float*)d_out;

    const int NB = (N + NPB - 1) / NPB;   // 391 (<= NBMAX required)

    char* w = (char*)d_ws;
    u16* B0 = (u16*)w; w += (size_t)N * H * sizeof(u16);
    u16* B1 = (u16*)w; w += (size_t)N * H * sizeof(u16);
    u16* packedW = (u16*)w; w += (size_t)6 * H * H * sizeof(u16);
    float* y    = (float*)w; w += (size_t)N * sizeof(float);
    int* offs   = (int*)w;   w += (size_t)(N + 1) * sizeof(int);
    int* bcnt   = (int*)w;   w += NBMAX * sizeof(int);
    int* boffs  = (int*)w;   w += (NBMAX + 1) * sizeof(int);
    int* bcursor= (int*)w;   w += NBMAX * sizeof(int);
    u32* stage  = (u32*)w;   w += (size_t)E * sizeof(u32);
    int* cols   = (int*)w;   w += (size_t)E * sizeof(int);

    hipMemsetAsync(bcnt, 0, NBMAX * sizeof(int), stream);

    // convert x -> bf16
    {
        int n4 = N * H / 4;
        convert_kernel<<<(n4 + 255) / 256, 256, 0, stream>>>(x, B0, n4);
    }
    // pack weights
    {
        int total = 6 * H * H;
        pack_w_kernel<<<(total + 255) / 256, 256, 0, stream>>>(W1, W2, packedW, total);
    }
    // CSR build (two-level bucket sort; no per-edge global atomics; grids sized for >1 block/CU)
    bucket_hist<<<1024, 256, 0, stream>>>(dstv, bcnt, E, NB);
    bucket_scan<<<1, 64, 0, stream>>>(bcnt, boffs, bcursor, NB);
    scatter_kernel<<<(E + SCHUNK - 1) / SCHUNK, 256, 0, stream>>>(src, dstv, bcursor, stage, E, NB);
    build_csr<<<NB, 256, 0, stream>>>(stage, boffs, offs, cols, N, NB, E);

    const int numTiles = (N + 15) / 16;   // 3125 -> one block per tile
    u16* bufs[2] = { B0, B1 };
    int cur = 0;
    for (int l = 0; l < L; ++l) {
        int nxt = cur ^ 1;
        int last = (l == L - 1) ? 1 : 0;
        fused_layer<<<numTiles, 256, 0, stream>>>(bufs[cur], bufs[nxt], offs, cols,
                                                  packedW + (size_t)l * H * H,
                                                  packedW + (size_t)(3 + l) * H * H,
                                                  b1 + (size_t)l * H, b2 + (size_t)l * H,
                                                  eps, l, (l < L - 1) ? 1 : 0, last,
                                                  Wh, y, N);
        cur = nxt;
    }

    seg_out_kernel<<<NGRAPH, 256, 0, stream>>>(y, batch, bh, out, N);
}

// Round 12
// 258.500 us; speedup vs baseline: 1.2082x; 1.2082x over previous
//
#include <hip/hip_runtime.h>
#include <cstdint>

#define H 128
#define NGRAPH 256
#define ROWSTRIDE 68   // u32 per LDS tile row (64 data + 4 pad) -> 2-way max bank conflict
#define NPB 256        // nodes per bucket (bucket = dst >> 8); requires N <= 65536
#define CSR_CAP 6144   // LDS staging entries per bucket (mean ~4080, +32 sigma safe)
// [R11 lesson: NPB=128/SCHUNK=1024 "grid fix" regressed 263->312 µs. Scatter is
//  write-amplification-bound, not latency-bound: run length per (block,bucket) =
//  SCHUNK/NB must stay ~20 edges (80B). Keep SCHUNK=4096, NB=196.]
#define SCHUNK 4096

typedef __attribute__((ext_vector_type(8))) short short8;
typedef __attribute__((ext_vector_type(4))) float floatx4;

typedef unsigned short u16;
typedef unsigned int u32;

__device__ __forceinline__ u16 f2b(float f) {
    union { float f; u32 u; } v; v.f = f;
    u32 r = v.u + 0x7fffu + ((v.u >> 16) & 1u);
    return (u16)(r >> 16);
}
// bare u16 bf16 -> float (ONE shift)
__device__ __forceinline__ float b2f(u16 b) {
    union { u32 u; float f; } v; v.u = ((u32)b) << 16;
    return v.f;
}
// packed-pair helpers: take the full u32 holding two bf16
__device__ __forceinline__ float lo_f(u32 v) {
    union { u32 u; float f; } w; w.u = v << 16; return w.f;
}
__device__ __forceinline__ float hi_f(u32 v) {
    union { u32 u; float f; } w; w.u = v & 0xffff0000u; return w.f;
}

// ------------------------- fp32 -> bf16 convert -------------------------
__global__ void convert_kernel(const float* __restrict__ in, u16* __restrict__ out, int n4) {
    int i = blockIdx.x * blockDim.x + threadIdx.x;
    if (i < n4) {
        float4 v = *(const float4*)(in + (size_t)i * 4);
        u16 o[4] = { f2b(v.x), f2b(v.y), f2b(v.z), f2b(v.w) };
        *(uint2*)(out + (size_t)i * 4) = *(uint2*)o;
    }
}

// ------------------------- pack W into MFMA B-fragment order -------------------------
// packed[mat][ ((kc*8+nt)*64 + lane)*8 + j ] = W[mat][k=kc*32+(lane>>4)*8+j][n=nt*16+(lane&15)]
__global__ void pack_w_kernel(const float* __restrict__ W1, const float* __restrict__ W2,
                              u16* __restrict__ packed, int total) {
    int idx = blockIdx.x * blockDim.x + threadIdx.x;
    if (idx >= total) return;
    int mat = idx >> 14;           // /16384
    int pos = idx & 16383;
    int j    = pos & 7;
    int lane = (pos >> 3) & 63;
    int nt   = (pos >> 9) & 7;
    int kc   = pos >> 12;
    int k = kc * 32 + (lane >> 4) * 8 + j;
    int n = nt * 16 + (lane & 15);
    const float* src = (mat < 3) ? (W1 + (size_t)mat * H * H) : (W2 + (size_t)(mat - 3) * H * H);
    packed[idx] = f2b(src[(size_t)k * H + n]);
}

// ------------------------- CSR build: two-level bucket sort -------------------------
__global__ __launch_bounds__(256) void bucket_hist(const int* __restrict__ dstv,
                                                   int* __restrict__ bcnt, int E, int NB) {
    __shared__ int sh[256];
    int t = threadIdx.x;
    sh[t] = 0;
    __syncthreads();
    for (int e = blockIdx.x * 256 + t; e < E; e += gridDim.x * 256)
        atomicAdd(&sh[dstv[e] >> 8], 1);
    __syncthreads();
    if (t < NB && sh[t] > 0) atomicAdd(&bcnt[t], sh[t]);
}

__global__ void bucket_scan(const int* __restrict__ bcnt, int* __restrict__ boffs,
                            int* __restrict__ bcursor, int NB) {
    if (threadIdx.x == 0 && blockIdx.x == 0) {
        int run = 0;
        for (int i = 0; i < NB; ++i) { boffs[i] = run; bcursor[i] = run; run += bcnt[i]; }
        boffs[NB] = run;
    }
}

__global__ __launch_bounds__(256) void scatter_kernel(const int* __restrict__ src,
                                                      const int* __restrict__ dstv,
                                                      int* __restrict__ bcursor,
                                                      u32* __restrict__ stage, int E, int NB) {
    __shared__ int lcnt[256];
    __shared__ int lbase[256];
    int t = threadIdx.x;
    lcnt[t] = 0;
    __syncthreads();
    int base = blockIdx.x * SCHUNK;
    u32 pk[16];
    int bk[16];
#pragma unroll
    for (int i = 0; i < 16; ++i) {
        int idx = base + t + i * 256;
        bk[i] = -1;
        if (idx < E) {
            int s = src[idx];
            int d = dstv[idx];
            int b = d >> 8;
            pk[i] = (u32)s | ((u32)(d & 255) << 24);   // src < 2^24
            bk[i] = b;
            atomicAdd(&lcnt[b], 1);
        }
    }
    __syncthreads();
    if (t < NB && lcnt[t] > 0) lbase[t] = atomicAdd(&bcursor[t], lcnt[t]);
    __syncthreads();
    lcnt[t] = 0;
    __syncthreads();
#pragma unroll
    for (int i = 0; i < 16; ++i) {
        if (bk[i] >= 0) {
            int r = atomicAdd(&lcnt[bk[i]], 1);
            stage[(size_t)lbase[bk[i]] + r] = pk[i];
        }
    }
}

__global__ __launch_bounds__(256) void build_csr(const u32* __restrict__ stage,
                                                 const int* __restrict__ boffs,
                                                 int* __restrict__ offs, int* __restrict__ cols,
                                                 int N, int NB, int E) {
    __shared__ int cnt[256];
    __shared__ int cur[256];
    __shared__ int sA[256];
    __shared__ int sB[256];
    __shared__ int colstage[CSR_CAP];
    int b = blockIdx.x;
    int t = threadIdx.x;
    int lo = boffs[b], hi = boffs[b + 1];
    int sz = hi - lo;
    int nlo = b * NPB;
    cnt[t] = 0;
    __syncthreads();
    for (int i = t; i < sz; i += 256) atomicAdd(&cnt[stage[(size_t)lo + i] >> 24], 1);
    __syncthreads();
    sA[t] = cnt[t];
    __syncthreads();
    int* a = sA; int* bb = sB;
    for (int off = 1; off < 256; off <<= 1) {
        bb[t] = (t >= off) ? (a[t] + a[t - off]) : a[t];
        __syncthreads();
        int* tmp = a; a = bb; bb = tmp;
    }
    int excl = a[t] - cnt[t];
    if (nlo + t < N) offs[nlo + t] = lo + excl;
    if (b == 0 && t == 0) offs[N] = E;
    cur[t] = excl;
    __syncthreads();
    if (sz <= CSR_CAP) {
        for (int i = t; i < sz; i += 256) {
            u32 pk = stage[(size_t)lo + i];
            int r = atomicAdd(&cur[pk >> 24], 1);
            colstage[r] = (int)(pk & 0xFFFFFFu);
        }
        __syncthreads();
        for (int i = t; i < sz; i += 256) cols[(size_t)lo + i] = colstage[i];
    } else {
        for (int i = t; i < sz; i += 256) {
            u32 pk = stage[(size_t)lo + i];
            int r = atomicAdd(&cur[pk >> 24], 1);
            cols[(size_t)lo + r] = (int)(pk & 0xFFFFFFu);
        }
    }
}

// ------------------------- fused GIN layer -------------------------
// One block per 16-node tile: gather (CSR) -> LDS -> MFMA GEMM1(+bias,ReLU) -> LDS ->
// MFMA GEMM2(+bias,opt ReLU) -> store (or, last layer, fused dot with Wh -> y).
// Gather: GROUP-PARALLEL (each 16-lane group owns one node, 4 nodes per wave in
// parallel) with edge-loop unroll x4 -> 16 independent row-loads in flight per wave.
// [R8 lesson: wave-sequential gather regressed — MLP > exec-mask efficiency.]
// [R10 lesson: dword->dwordx4 was neutral-to-slightly-worse — gather is not issue-bound;
//  it sits at the L2/L3 random-access plateau (~4.9 TB/s effective). This dword version
//  measured best (R9: 258.6 µs).]
__global__ __launch_bounds__(256) void fused_layer(const u16* __restrict__ h,
                                                   u16* __restrict__ hout,
                                                   const int* __restrict__ offs,
                                                   const int* __restrict__ cols,
                                                   const u16* __restrict__ Wp1,
                                                   const u16* __restrict__ Wp2,
                                                   const float* __restrict__ bias1,
                                                   const float* __restrict__ bias2,
                                                   const float* __restrict__ eps, int layer,
                                                   int relu2, int lastLayer,
                                                   const float* __restrict__ Wh,
                                                   float* __restrict__ y, int N) {
    __shared__ u32 ldsA[16 * ROWSTRIDE];
    __shared__ u32 ldsB[16 * ROWSTRIDE];
    __shared__ float dacc[16];

    const int tid = threadIdx.x;
    const int wave = tid >> 6;
    const int lane = tid & 63;
    const int m = lane & 15;
    const int quad = lane >> 4;
    const int nt0 = wave * 2, nt1 = wave * 2 + 1;
    const int row0 = blockIdx.x * 16;

    const float scale = 1.0f + eps[layer];
    const u32* __restrict__ hp = (const u32*)h;

    // ---- gather: group-parallel; lane covers 4 u32 (8 feats) of its group's node ----
    {
        const int nid = wave * 4 + quad;       // 0..15
        const int node = row0 + nid;
        float a[8];
#pragma unroll
        for (int i = 0; i < 8; ++i) a[i] = 0.f;
        if (node < N) {
#pragma unroll
            for (int i = 0; i < 4; ++i) {
                u32 v = hp[(size_t)node * 64 + m + 16 * i];
                a[2 * i]     = scale * lo_f(v);
                a[2 * i + 1] = scale * hi_f(v);
            }
            int beg = offs[node], end = offs[node + 1];
            int j = beg;
            for (; j + 4 <= end; j += 4) {
                int c0 = cols[j], c1 = cols[j + 1], c2 = cols[j + 2], c3 = cols[j + 3];
                u32 v0[4], v1[4], v2[4], v3[4];
#pragma unroll
                for (int i = 0; i < 4; ++i) v0[i] = hp[(size_t)c0 * 64 + m + 16 * i];
#pragma unroll
                for (int i = 0; i < 4; ++i) v1[i] = hp[(size_t)c1 * 64 + m + 16 * i];
#pragma unroll
                for (int i = 0; i < 4; ++i) v2[i] = hp[(size_t)c2 * 64 + m + 16 * i];
#pragma unroll
                for (int i = 0; i < 4; ++i) v3[i] = hp[(size_t)c3 * 64 + m + 16 * i];
#pragma unroll
                for (int i = 0; i < 4; ++i) {
                    a[2 * i]     += (lo_f(v0[i]) + lo_f(v1[i])) + (lo_f(v2[i]) + lo_f(v3[i]));
                    a[2 * i + 1] += (hi_f(v0[i]) + hi_f(v1[i])) + (hi_f(v2[i]) + hi_f(v3[i]));
                }
            }
            for (; j < end; ++j) {
                int c0 = cols[j];
#pragma unroll
                for (int i = 0; i < 4; ++i) {
                    u32 v = hp[(size_t)c0 * 64 + m + 16 * i];
                    a[2 * i]     += lo_f(v);
                    a[2 * i + 1] += hi_f(v);
                }
            }
        }
#pragma unroll
        for (int i = 0; i < 4; ++i) {
            u16 p[2] = { f2b(a[2 * i]), f2b(a[2 * i + 1]) };
            ldsA[nid * ROWSTRIDE + m + 16 * i] = *(u32*)p;
        }
    }

    // B fragments (loaded in the gather's latency shadow)
    short8 B1f0[4], B1f1[4], B2f0[4], B2f1[4];
#pragma unroll
    for (int kc = 0; kc < 4; ++kc) {
        B1f0[kc] = *(const short8*)(Wp1 + ((size_t)(kc * 8 + nt0) * 64 + lane) * 8);
        B1f1[kc] = *(const short8*)(Wp1 + ((size_t)(kc * 8 + nt1) * 64 + lane) * 8);
        B2f0[kc] = *(const short8*)(Wp2 + ((size_t)(kc * 8 + nt0) * 64 + lane) * 8);
        B2f1[kc] = *(const short8*)(Wp2 + ((size_t)(kc * 8 + nt1) * 64 + lane) * 8);
    }
    const int cg0 = nt0 * 16 + m, cg1 = nt1 * 16 + m;
    const float b1v0 = bias1[cg0], b1v1 = bias1[cg1];
    const float b2v0 = bias2[cg0], b2v1 = bias2[cg1];
    __syncthreads();

    // ---- GEMM1: z1 = relu(z0 @ W1 + b1) ----
    {
        short8 a0 = *(const short8*)(&ldsA[m * ROWSTRIDE + 0 * 16 + quad * 4]);
        short8 a1 = *(const short8*)(&ldsA[m * ROWSTRIDE + 1 * 16 + quad * 4]);
        short8 a2 = *(const short8*)(&ldsA[m * ROWSTRIDE + 2 * 16 + quad * 4]);
        short8 a3 = *(const short8*)(&ldsA[m * ROWSTRIDE + 3 * 16 + quad * 4]);
        floatx4 acc0 = {0.f, 0.f, 0.f, 0.f};
        floatx4 acc1 = {0.f, 0.f, 0.f, 0.f};
        acc0 = __builtin_amdgcn_mfma_f32_16x16x32_bf16(a0, B1f0[0], acc0, 0, 0, 0);
        acc1 = __builtin_amdgcn_mfma_f32_16x16x32_bf16(a0, B1f1[0], acc1, 0, 0, 0);
        acc0 = __builtin_amdgcn_mfma_f32_16x16x32_bf16(a1, B1f0[1], acc0, 0, 0, 0);
        acc1 = __builtin_amdgcn_mfma_f32_16x16x32_bf16(a1, B1f1[1], acc1, 0, 0, 0);
        acc0 = __builtin_amdgcn_mfma_f32_16x16x32_bf16(a2, B1f0[2], acc0, 0, 0, 0);
        acc1 = __builtin_amdgcn_mfma_f32_16x16x32_bf16(a2, B1f1[2], acc1, 0, 0, 0);
        acc0 = __builtin_amdgcn_mfma_f32_16x16x32_bf16(a3, B1f0[3], acc0, 0, 0, 0);
        acc1 = __builtin_amdgcn_mfma_f32_16x16x32_bf16(a3, B1f1[3], acc1, 0, 0, 0);
        u16* lb = (u16*)ldsB;
#pragma unroll
        for (int i = 0; i < 4; ++i) {
            int rr = quad * 4 + i;
            lb[rr * (ROWSTRIDE * 2) + cg0] = f2b(fmaxf(acc0[i] + b1v0, 0.f));
            lb[rr * (ROWSTRIDE * 2) + cg1] = f2b(fmaxf(acc1[i] + b1v1, 0.f));
        }
        if (tid < 16) dacc[tid] = 0.f;
    }
    __syncthreads();

    // ---- GEMM2: z2 = (relu?)(z1 @ W2 + b2) ----
    {
        short8 a0 = *(const short8*)(&ldsB[m * ROWSTRIDE + 0 * 16 + quad * 4]);
        short8 a1 = *(const short8*)(&ldsB[m * ROWSTRIDE + 1 * 16 + quad * 4]);
        short8 a2 = *(const short8*)(&ldsB[m * ROWSTRIDE + 2 * 16 + quad * 4]);
        short8 a3 = *(const short8*)(&ldsB[m * ROWSTRIDE + 3 * 16 + quad * 4]);
        floatx4 acc0 = {0.f, 0.f, 0.f, 0.f};
        floatx4 acc1 = {0.f, 0.f, 0.f, 0.f};
        acc0 = __builtin_amdgcn_mfma_f32_16x16x32_bf16(a0, B2f0[0], acc0, 0, 0, 0);
        acc1 = __builtin_amdgcn_mfma_f32_16x16x32_bf16(a0, B2f1[0], acc1, 0, 0, 0);
        acc0 = __builtin_amdgcn_mfma_f32_16x16x32_bf16(a1, B2f0[1], acc0, 0, 0, 0);
        acc1 = __builtin_amdgcn_mfma_f32_16x16x32_bf16(a1, B2f1[1], acc1, 0, 0, 0);
        acc0 = __builtin_amdgcn_mfma_f32_16x16x32_bf16(a2, B2f0[2], acc0, 0, 0, 0);
        acc1 = __builtin_amdgcn_mfma_f32_16x16x32_bf16(a2, B2f1[2], acc1, 0, 0, 0);
        acc0 = __builtin_amdgcn_mfma_f32_16x16x32_bf16(a3, B2f0[3], acc0, 0, 0, 0);
        acc1 = __builtin_amdgcn_mfma_f32_16x16x32_bf16(a3, B2f1[3], acc1, 0, 0, 0);

        if (!lastLayer) {
            u16* la = (u16*)ldsA;
#pragma unroll
            for (int i = 0; i < 4; ++i) {
                int rr = quad * 4 + i;
                float v0 = acc0[i] + b2v0;
                float v1 = acc1[i] + b2v1;
                if (relu2) { v0 = fmaxf(v0, 0.f); v1 = fmaxf(v1, 0.f); }
                la[rr * (ROWSTRIDE * 2) + cg0] = f2b(v0);
                la[rr * (ROWSTRIDE * 2) + cg1] = f2b(v1);
            }
            __syncthreads();
            // coalesced store: each thread copies 16B
            int rr = tid >> 4;
            int s  = tid & 15;
            int grow = row0 + rr;
            if (grow < N) {
                uint4 v = *(uint4*)(&ldsA[rr * ROWSTRIDE + s * 4]);
                *(uint4*)(hout + (size_t)grow * H + s * 8) = v;
            }
        } else {
            // fused head: y[row] = sum_c bf16(z2[row][c]) * Wh[c]
            const float wh0 = Wh[cg0], wh1 = Wh[cg1];
            float part[4];
#pragma unroll
            for (int i = 0; i < 4; ++i)
                part[i] = b2f(f2b(acc0[i] + b2v0)) * wh0 +
                          b2f(f2b(acc1[i] + b2v1)) * wh1;
            // reduce across the 16 lanes of each quad group (xor masks < 16 stay in-group)
#pragma unroll
            for (int off = 1; off < 16; off <<= 1)
#pragma unroll
                for (int i = 0; i < 4; ++i) part[i] += __shfl_xor(part[i], off, 64);
            if (m == 0) {
#pragma unroll
                for (int i = 0; i < 4; ++i) atomicAdd(&dacc[quad * 4 + i], part[i]);
            }
            __syncthreads();
            if (tid < 16 && row0 + tid < N) y[row0 + tid] = dacc[tid];
        }
    }
}

// ------------------------- per-graph mean via binary search on sorted batch -------------------------
__device__ __forceinline__ int lbound(const int* __restrict__ a, int n, int v) {
    int lo = 0, hi = n;
    while (lo < hi) { int mid = (lo + hi) >> 1; if (a[mid] < v) lo = mid + 1; else hi = mid; }
    return lo;
}

__global__ void seg_out_kernel(const float* __restrict__ y, const int* __restrict__ batch,
                               const float* __restrict__ bh, float* __restrict__ out, int N) {
    __shared__ float sh[256];
    int g = blockIdx.x;
    int lo = lbound(batch, N, g);
    int hi = lbound(batch, N, g + 1);
    float s = 0.f;
    for (int i = lo + threadIdx.x; i < hi; i += 256) s += y[i];
    sh[threadIdx.x] = s;
    __syncthreads();
    for (int off = 128; off > 0; off >>= 1) {
        if (threadIdx.x < off) sh[threadIdx.x] += sh[threadIdx.x + off];
        __syncthreads();
    }
    if (threadIdx.x == 0) {
        float cnt = (float)(hi - lo);
        out[g] = sh[0] / fmaxf(cnt, 1.0f) + bh[0];
    }
}

// ------------------------- launch -------------------------
extern "C" void kernel_launch(void* const* d_in, const int* in_sizes, int n_in,
                              void* d_out, int out_size, void* d_ws, size_t ws_size,
                              hipStream_t stream) {
    const float* x    = (const float*)d_in[0];
    const int*   eidx = (const int*)d_in[1];
    const int*   batch= (const int*)d_in[2];
    const float* W1   = (const float*)d_in[3];
    const float* b1   = (const float*)d_in[4];
    const float* W2   = (const float*)d_in[5];
    const float* b2   = (const float*)d_in[6];
    const float* eps  = (const float*)d_in[7];
    const float* Wh   = (const float*)d_in[8];
    const float* bh   = (const float*)d_in[9];

    const int N = in_sizes[0] / H;   // 50000
    const int E = in_sizes[1] / 2;   // 800000
    const int L = in_sizes[7];       // 3
    const int* src  = eidx;
    const int* dstv = eidx + E;
    float* out = (float*)d_out;

    const int NB = (N + NPB - 1) / NPB;   // 196 (<= 256 required)

    char* w = (char*)d_ws;
    u16* B0 = (u16*)w; w += (size_t)N * H * sizeof(u16);
    u16* B1 = (u16*)w; w += (size_t)N * H * sizeof(u16);
    u16* packedW = (u16*)w; w += (size_t)6 * H * H * sizeof(u16);
    float* y    = (float*)w; w += (size_t)N * sizeof(float);
    int* offs   = (int*)w;   w += (size_t)(N + 1) * sizeof(int);
    int* bcnt   = (int*)w;   w += 256 * sizeof(int);
    int* boffs  = (int*)w;   w += 257 * sizeof(int);
    int* bcursor= (int*)w;   w += 256 * sizeof(int);
    u32* stage  = (u32*)w;   w += (size_t)E * sizeof(u32);
    int* cols   = (int*)w;   w += (size_t)E * sizeof(int);

    hipMemsetAsync(bcnt, 0, 256 * sizeof(int), stream);

    // convert x -> bf16
    {
        int n4 = N * H / 4;
        convert_kernel<<<(n4 + 255) / 256, 256, 0, stream>>>(x, B0, n4);
    }
    // pack weights
    {
        int total = 6 * H * H;
        pack_w_kernel<<<(total + 255) / 256, 256, 0, stream>>>(W1, W2, packedW, total);
    }
    // CSR build (two-level bucket sort; no per-edge global atomics)
    bucket_hist<<<256, 256, 0, stream>>>(dstv, bcnt, E, NB);
    bucket_scan<<<1, 64, 0, stream>>>(bcnt, boffs, bcursor, NB);
    scatter_kernel<<<(E + SCHUNK - 1) / SCHUNK, 256, 0, stream>>>(src, dstv, bcursor, stage, E, NB);
    build_csr<<<NB, 256, 0, stream>>>(stage, boffs, offs, cols, N, NB, E);

    const int numTiles = (N + 15) / 16;   // 3125 -> one block per tile
    u16* bufs[2] = { B0, B1 };
    int cur = 0;
    for (int l = 0; l < L; ++l) {
        int nxt = cur ^ 1;
        int last = (l == L - 1) ? 1 : 0;
        fused_layer<<<numTiles, 256, 0, stream>>>(bufs[cur], bufs[nxt], offs, cols,
                                                  packedW + (size_t)l * H * H,
                                                  packedW + (size_t)(3 + l) * H * H,
                                                  b1 + (size_t)l * H, b2 + (size_t)l * H,
                                                  eps, l, (l < L - 1) ? 1 : 0, last,
                                                  Wh, y, N);
        cur = nxt;
    }

    seg_out_kernel<<<NGRAPH, 256, 0, stream>>>(y, batch, bh, out, N);
}

// Round 13
// 245.415 us; speedup vs baseline: 1.2726x; 1.0533x over previous
//
#include <hip/hip_runtime.h>
#include <cstdint>

#define H 128
#define NGRAPH 256
#define ROWSTRIDE 68   // u32 per LDS tile row (64 data + 4 pad) -> 2-way max bank conflict
#define NPB 256        // nodes per bucket (bucket = dst >> 8); requires N <= 65536
#define CSR_CAP 6144   // LDS staging entries per bucket (mean ~4080, +32 sigma safe)
// [R11 lesson: NPB=128/SCHUNK=1024 "grid fix" regressed 263->312 µs. Scatter is
//  write-amplification-bound, not latency-bound: run length per (block,bucket) =
//  SCHUNK/NB must stay ~20 edges (80B). Keep SCHUNK=4096, NB=196.]
#define SCHUNK 4096

typedef __attribute__((ext_vector_type(8))) short short8;
typedef __attribute__((ext_vector_type(4))) float floatx4;

typedef unsigned short u16;
typedef unsigned int u32;

__device__ __forceinline__ u16 f2b(float f) {
    union { float f; u32 u; } v; v.f = f;
    u32 r = v.u + 0x7fffu + ((v.u >> 16) & 1u);
    return (u16)(r >> 16);
}
// bare u16 bf16 -> float (ONE shift)
__device__ __forceinline__ float b2f(u16 b) {
    union { u32 u; float f; } v; v.u = ((u32)b) << 16;
    return v.f;
}
// packed-pair helpers: take the full u32 holding two bf16
__device__ __forceinline__ float lo_f(u32 v) {
    union { u32 u; float f; } w; w.u = v << 16; return w.f;
}
__device__ __forceinline__ float hi_f(u32 v) {
    union { u32 u; float f; } w; w.u = v & 0xffff0000u; return w.f;
}

// ------------------------- prep: convert x->bf16 | pack W | bucket hist -------------------------
// [R13: merged 3 kernels into one block-role-dispatch launch to cut graph dispatch count]
__global__ __launch_bounds__(256) void prep_kernel(const float* __restrict__ x,
                                                   u16* __restrict__ xb,
                                                   const float* __restrict__ W1,
                                                   const float* __restrict__ W2,
                                                   u16* __restrict__ packed,
                                                   const int* __restrict__ dstv,
                                                   int* __restrict__ bcnt,
                                                   int n4, int total, int E, int NB,
                                                   int nConv, int nPack) {
    __shared__ int sh[256];
    const int t = threadIdx.x;
    const int b = blockIdx.x;
    if (b < nConv) {
        // convert
        int i = b * 256 + t;
        if (i < n4) {
            float4 v = *(const float4*)(x + (size_t)i * 4);
            u16 o[4] = { f2b(v.x), f2b(v.y), f2b(v.z), f2b(v.w) };
            *(uint2*)(xb + (size_t)i * 4) = *(uint2*)o;
        }
    } else if (b < nConv + nPack) {
        // pack W into MFMA B-fragment order:
        // packed[mat][((kc*8+nt)*64+lane)*8+j] = W[mat][k=kc*32+(lane>>4)*8+j][n=nt*16+(lane&15)]
        int idx = (b - nConv) * 256 + t;
        if (idx < total) {
            int mat = idx >> 14;
            int pos = idx & 16383;
            int j    = pos & 7;
            int lane = (pos >> 3) & 63;
            int nt   = (pos >> 9) & 7;
            int kc   = pos >> 12;
            int k = kc * 32 + (lane >> 4) * 8 + j;
            int n = nt * 16 + (lane & 15);
            const float* src = (mat < 3) ? (W1 + (size_t)mat * H * H)
                                         : (W2 + (size_t)(mat - 3) * H * H);
            packed[idx] = f2b(src[(size_t)k * H + n]);
        }
    } else {
        // bucket histogram (LDS-local, one global atomic per bucket per block)
        int bb = b - nConv - nPack;          // 0..255
        sh[t] = 0;
        __syncthreads();
        for (int e = bb * 256 + t; e < E; e += 256 * 256)
            atomicAdd(&sh[dstv[e] >> 8], 1);
        __syncthreads();
        if (t < NB && sh[t] > 0) atomicAdd(&bcnt[t], sh[t]);
    }
}

// ------------------------- scatter into bucket-contiguous staging -------------------------
// Computes boffs via in-block LDS scan of bcnt (196 entries); bcursor holds RELATIVE
// offsets (zero-initialized by the host memset). One global atomic per (block,bucket).
__global__ __launch_bounds__(256) void scatter_kernel(const int* __restrict__ src,
                                                      const int* __restrict__ dstv,
                                                      const int* __restrict__ bcnt,
                                                      int* __restrict__ bcursor,
                                                      u32* __restrict__ stage, int E, int NB) {
    __shared__ int lcnt[256];
    __shared__ int lbase[256];
    __shared__ int sA[256];
    __shared__ int sB[256];
    int t = threadIdx.x;
    // in-block exclusive scan of bcnt -> sB = boffs
    int v = (t < NB) ? bcnt[t] : 0;
    sA[t] = v;
    lcnt[t] = 0;
    __syncthreads();
    int* a = sA; int* bb2 = sB;
    for (int off = 1; off < 256; off <<= 1) {
        bb2[t] = (t >= off) ? (a[t] + a[t - off]) : a[t];
        __syncthreads();
        int* tmp = a; a = bb2; bb2 = tmp;
    }
    // after 8 iters a == sA (even swaps); write exclusive prefix into sB
    bb2[t] = a[t] - v;   // bb2 == sB
    __syncthreads();

    int base = blockIdx.x * SCHUNK;
    u32 pk[16];
    int bk[16];
#pragma unroll
    for (int i = 0; i < 16; ++i) {
        int idx = base + t + i * 256;
        bk[i] = -1;
        if (idx < E) {
            int s = src[idx];
            int d = dstv[idx];
            int b = d >> 8;
            pk[i] = (u32)s | ((u32)(d & 255) << 24);   // src < 2^24
            bk[i] = b;
            atomicAdd(&lcnt[b], 1);
        }
    }
    __syncthreads();
    if (t < NB && lcnt[t] > 0) lbase[t] = sB[t] + atomicAdd(&bcursor[t], lcnt[t]);
    __syncthreads();
    lcnt[t] = 0;
    __syncthreads();
#pragma unroll
    for (int i = 0; i < 16; ++i) {
        if (bk[i] >= 0) {
            int r = atomicAdd(&lcnt[bk[i]], 1);
            stage[(size_t)lbase[bk[i]] + r] = pk[i];
        }
    }
}

// ------------------------- build CSR from staged buckets -------------------------
// One block per bucket; computes its own lo/hi via in-block scan of bcnt. Per-node
// count -> LDS scan -> offs (coalesced) -> LDS col scatter -> linear write-out.
__global__ __launch_bounds__(256) void build_csr(const u32* __restrict__ stage,
                                                 const int* __restrict__ bcnt,
                                                 int* __restrict__ offs, int* __restrict__ cols,
                                                 int N, int NB, int E) {
    __shared__ int cnt[256];
    __shared__ int cur[256];
    __shared__ int sA[256];
    __shared__ int sB[256];
    __shared__ int colstage[CSR_CAP];
    int b = blockIdx.x;
    int t = threadIdx.x;
    // in-block inclusive scan of bcnt -> lo/hi for this bucket
    int v = (t < NB) ? bcnt[t] : 0;
    sA[t] = v;
    __syncthreads();
    int* a = sA; int* bb2 = sB;
    for (int off = 1; off < 256; off <<= 1) {
        bb2[t] = (t >= off) ? (a[t] + a[t - off]) : a[t];
        __syncthreads();
        int* tmp = a; a = bb2; bb2 = tmp;
    }
    int lo = (b == 0) ? 0 : a[b - 1];
    int hi = a[b];
    __syncthreads();          // sA/sB reused below
    int sz = hi - lo;
    int nlo = b * NPB;
    cnt[t] = 0;
    __syncthreads();
    for (int i = t; i < sz; i += 256) atomicAdd(&cnt[stage[(size_t)lo + i] >> 24], 1);
    __syncthreads();
    sA[t] = cnt[t];
    __syncthreads();
    a = sA; bb2 = sB;
    for (int off = 1; off < 256; off <<= 1) {
        bb2[t] = (t >= off) ? (a[t] + a[t - off]) : a[t];
        __syncthreads();
        int* tmp = a; a = bb2; bb2 = tmp;
    }
    int excl = a[t] - cnt[t];
    if (nlo + t < N) offs[nlo + t] = lo + excl;
    if (b == 0 && t == 0) offs[N] = E;
    cur[t] = excl;
    __syncthreads();
    if (sz <= CSR_CAP) {
        for (int i = t; i < sz; i += 256) {
            u32 pk = stage[(size_t)lo + i];
            int r = atomicAdd(&cur[pk >> 24], 1);
            colstage[r] = (int)(pk & 0xFFFFFFu);
        }
        __syncthreads();
        for (int i = t; i < sz; i += 256) cols[(size_t)lo + i] = colstage[i];
    } else {
        for (int i = t; i < sz; i += 256) {
            u32 pk = stage[(size_t)lo + i];
            int r = atomicAdd(&cur[pk >> 24], 1);
            cols[(size_t)lo + r] = (int)(pk & 0xFFFFFFu);
        }
    }
}

// ------------------------- fused GIN layer -------------------------
// One block per 16-node tile: gather (CSR) -> LDS -> MFMA GEMM1(+bias,ReLU) -> LDS ->
// MFMA GEMM2(+bias,opt ReLU) -> store (or, last layer, fused dot with Wh -> y).
// Gather: GROUP-PARALLEL (each 16-lane group owns one node, 4 nodes per wave in
// parallel) with edge-loop unroll x4 -> 16 independent row-loads in flight per wave.
// [R8: wave-sequential gather regressed — MLP > exec-mask efficiency.]
// [R10: dword->dwordx4 neutral — gather is at the L2/L3 random-access plateau
//  (~5 TB/s effective); this dword version measured best (R9/R12: 258.5 µs).]
__global__ __launch_bounds__(256) void fused_layer(const u16* __restrict__ h,
                                                   u16* __restrict__ hout,
                                                   const int* __restrict__ offs,
                                                   const int* __restrict__ cols,
                                                   const u16* __restrict__ Wp1,
                                                   const u16* __restrict__ Wp2,
                                                   const float* __restrict__ bias1,
                                                   const float* __restrict__ bias2,
                                                   const float* __restrict__ eps, int layer,
                                                   int relu2, int lastLayer,
                                                   const float* __restrict__ Wh,
                                                   float* __restrict__ y, int N) {
    __shared__ u32 ldsA[16 * ROWSTRIDE];
    __shared__ u32 ldsB[16 * ROWSTRIDE];
    __shared__ float dacc[16];

    const int tid = threadIdx.x;
    const int wave = tid >> 6;
    const int lane = tid & 63;
    const int m = lane & 15;
    const int quad = lane >> 4;
    const int nt0 = wave * 2, nt1 = wave * 2 + 1;
    const int row0 = blockIdx.x * 16;

    const float scale = 1.0f + eps[layer];
    const u32* __restrict__ hp = (const u32*)h;

    // ---- gather: group-parallel; lane covers 4 u32 (8 feats) of its group's node ----
    {
        const int nid = wave * 4 + quad;       // 0..15
        const int node = row0 + nid;
        float a[8];
#pragma unroll
        for (int i = 0; i < 8; ++i) a[i] = 0.f;
        if (node < N) {
#pragma unroll
            for (int i = 0; i < 4; ++i) {
                u32 v = hp[(size_t)node * 64 + m + 16 * i];
                a[2 * i]     = scale * lo_f(v);
                a[2 * i + 1] = scale * hi_f(v);
            }
            int beg = offs[node], end = offs[node + 1];
            int j = beg;
            for (; j + 4 <= end; j += 4) {
                int c0 = cols[j], c1 = cols[j + 1], c2 = cols[j + 2], c3 = cols[j + 3];
                u32 v0[4], v1[4], v2[4], v3[4];
#pragma unroll
                for (int i = 0; i < 4; ++i) v0[i] = hp[(size_t)c0 * 64 + m + 16 * i];
#pragma unroll
                for (int i = 0; i < 4; ++i) v1[i] = hp[(size_t)c1 * 64 + m + 16 * i];
#pragma unroll
                for (int i = 0; i < 4; ++i) v2[i] = hp[(size_t)c2 * 64 + m + 16 * i];
#pragma unroll
                for (int i = 0; i < 4; ++i) v3[i] = hp[(size_t)c3 * 64 + m + 16 * i];
#pragma unroll
                for (int i = 0; i < 4; ++i) {
                    a[2 * i]     += (lo_f(v0[i]) + lo_f(v1[i])) + (lo_f(v2[i]) + lo_f(v3[i]));
                    a[2 * i + 1] += (hi_f(v0[i]) + hi_f(v1[i])) + (hi_f(v2[i]) + hi_f(v3[i]));
                }
            }
            for (; j < end; ++j) {
                int c0 = cols[j];
#pragma unroll
                for (int i = 0; i < 4; ++i) {
                    u32 v = hp[(size_t)c0 * 64 + m + 16 * i];
                    a[2 * i]     += lo_f(v);
                    a[2 * i + 1] += hi_f(v);
                }
            }
        }
#pragma unroll
        for (int i = 0; i < 4; ++i) {
            u16 p[2] = { f2b(a[2 * i]), f2b(a[2 * i + 1]) };
            ldsA[nid * ROWSTRIDE + m + 16 * i] = *(u32*)p;
        }
    }

    // B fragments (loaded in the gather's latency shadow)
    short8 B1f0[4], B1f1[4], B2f0[4], B2f1[4];
#pragma unroll
    for (int kc = 0; kc < 4; ++kc) {
        B1f0[kc] = *(const short8*)(Wp1 + ((size_t)(kc * 8 + nt0) * 64 + lane) * 8);
        B1f1[kc] = *(const short8*)(Wp1 + ((size_t)(kc * 8 + nt1) * 64 + lane) * 8);
        B2f0[kc] = *(const short8*)(Wp2 + ((size_t)(kc * 8 + nt0) * 64 + lane) * 8);
        B2f1[kc] = *(const short8*)(Wp2 + ((size_t)(kc * 8 + nt1) * 64 + lane) * 8);
    }
    const int cg0 = nt0 * 16 + m, cg1 = nt1 * 16 + m;
    const float b1v0 = bias1[cg0], b1v1 = bias1[cg1];
    const float b2v0 = bias2[cg0], b2v1 = bias2[cg1];
    __syncthreads();

    // ---- GEMM1: z1 = relu(z0 @ W1 + b1) ----
    {
        short8 a0 = *(const short8*)(&ldsA[m * ROWSTRIDE + 0 * 16 + quad * 4]);
        short8 a1 = *(const short8*)(&ldsA[m * ROWSTRIDE + 1 * 16 + quad * 4]);
        short8 a2 = *(const short8*)(&ldsA[m * ROWSTRIDE + 2 * 16 + quad * 4]);
        short8 a3 = *(const short8*)(&ldsA[m * ROWSTRIDE + 3 * 16 + quad * 4]);
        floatx4 acc0 = {0.f, 0.f, 0.f, 0.f};
        floatx4 acc1 = {0.f, 0.f, 0.f, 0.f};
        acc0 = __builtin_amdgcn_mfma_f32_16x16x32_bf16(a0, B1f0[0], acc0, 0, 0, 0);
        acc1 = __builtin_amdgcn_mfma_f32_16x16x32_bf16(a0, B1f1[0], acc1, 0, 0, 0);
        acc0 = __builtin_amdgcn_mfma_f32_16x16x32_bf16(a1, B1f0[1], acc0, 0, 0, 0);
        acc1 = __builtin_amdgcn_mfma_f32_16x16x32_bf16(a1, B1f1[1], acc1, 0, 0, 0);
        acc0 = __builtin_amdgcn_mfma_f32_16x16x32_bf16(a2, B1f0[2], acc0, 0, 0, 0);
        acc1 = __builtin_amdgcn_mfma_f32_16x16x32_bf16(a2, B1f1[2], acc1, 0, 0, 0);
        acc0 = __builtin_amdgcn_mfma_f32_16x16x32_bf16(a3, B1f0[3], acc0, 0, 0, 0);
        acc1 = __builtin_amdgcn_mfma_f32_16x16x32_bf16(a3, B1f1[3], acc1, 0, 0, 0);
        u16* lb = (u16*)ldsB;
#pragma unroll
        for (int i = 0; i < 4; ++i) {
            int rr = quad * 4 + i;
            lb[rr * (ROWSTRIDE * 2) + cg0] = f2b(fmaxf(acc0[i] + b1v0, 0.f));
            lb[rr * (ROWSTRIDE * 2) + cg1] = f2b(fmaxf(acc1[i] + b1v1, 0.f));
        }
        if (tid < 16) dacc[tid] = 0.f;
    }
    __syncthreads();

    // ---- GEMM2: z2 = (relu?)(z1 @ W2 + b2) ----
    {
        short8 a0 = *(const short8*)(&ldsB[m * ROWSTRIDE + 0 * 16 + quad * 4]);
        short8 a1 = *(const short8*)(&ldsB[m * ROWSTRIDE + 1 * 16 + quad * 4]);
        short8 a2 = *(const short8*)(&ldsB[m * ROWSTRIDE + 2 * 16 + quad * 4]);
        short8 a3 = *(const short8*)(&ldsB[m * ROWSTRIDE + 3 * 16 + quad * 4]);
        floatx4 acc0 = {0.f, 0.f, 0.f, 0.f};
        floatx4 acc1 = {0.f, 0.f, 0.f, 0.f};
        acc0 = __builtin_amdgcn_mfma_f32_16x16x32_bf16(a0, B2f0[0], acc0, 0, 0, 0);
        acc1 = __builtin_amdgcn_mfma_f32_16x16x32_bf16(a0, B2f1[0], acc1, 0, 0, 0);
        acc0 = __builtin_amdgcn_mfma_f32_16x16x32_bf16(a1, B2f0[1], acc0, 0, 0, 0);
        acc1 = __builtin_amdgcn_mfma_f32_16x16x32_bf16(a1, B2f1[1], acc1, 0, 0, 0);
        acc0 = __builtin_amdgcn_mfma_f32_16x16x32_bf16(a2, B2f0[2], acc0, 0, 0, 0);
        acc1 = __builtin_amdgcn_mfma_f32_16x16x32_bf16(a2, B2f1[2], acc1, 0, 0, 0);
        acc0 = __builtin_amdgcn_mfma_f32_16x16x32_bf16(a3, B2f0[3], acc0, 0, 0, 0);
        acc1 = __builtin_amdgcn_mfma_f32_16x16x32_bf16(a3, B2f1[3], acc1, 0, 0, 0);

        if (!lastLayer) {
            u16* la = (u16*)ldsA;
#pragma unroll
            for (int i = 0; i < 4; ++i) {
                int rr = quad * 4 + i;
                float v0 = acc0[i] + b2v0;
                float v1 = acc1[i] + b2v1;
                if (relu2) { v0 = fmaxf(v0, 0.f); v1 = fmaxf(v1, 0.f); }
                la[rr * (ROWSTRIDE * 2) + cg0] = f2b(v0);
                la[rr * (ROWSTRIDE * 2) + cg1] = f2b(v1);
            }
            __syncthreads();
            // coalesced store: each thread copies 16B
            int rr = tid >> 4;
            int s  = tid & 15;
            int grow = row0 + rr;
            if (grow < N) {
                uint4 v = *(uint4*)(&ldsA[rr * ROWSTRIDE + s * 4]);
                *(uint4*)(hout + (size_t)grow * H + s * 8) = v;
            }
        } else {
            // fused head: y[row] = sum_c bf16(z2[row][c]) * Wh[c]
            const float wh0 = Wh[cg0], wh1 = Wh[cg1];
            float part[4];
#pragma unroll
            for (int i = 0; i < 4; ++i)
                part[i] = b2f(f2b(acc0[i] + b2v0)) * wh0 +
                          b2f(f2b(acc1[i] + b2v1)) * wh1;
            // reduce across the 16 lanes of each quad group (xor masks < 16 stay in-group)
#pragma unroll
            for (int off = 1; off < 16; off <<= 1)
#pragma unroll
                for (int i = 0; i < 4; ++i) part[i] += __shfl_xor(part[i], off, 64);
            if (m == 0) {
#pragma unroll
                for (int i = 0; i < 4; ++i) atomicAdd(&dacc[quad * 4 + i], part[i]);
            }
            __syncthreads();
            if (tid < 16 && row0 + tid < N) y[row0 + tid] = dacc[tid];
        }
    }
}

// ------------------------- per-graph mean via binary search on sorted batch -------------------------
__device__ __forceinline__ int lbound(const int* __restrict__ a, int n, int v) {
    int lo = 0, hi = n;
    while (lo < hi) { int mid = (lo + hi) >> 1; if (a[mid] < v) lo = mid + 1; else hi = mid; }
    return lo;
}

__global__ void seg_out_kernel(const float* __restrict__ y, const int* __restrict__ batch,
                               const float* __restrict__ bh, float* __restrict__ out, int N) {
    __shared__ float sh[256];
    int g = blockIdx.x;
    int lo = lbound(batch, N, g);
    int hi = lbound(batch, N, g + 1);
    float s = 0.f;
    for (int i = lo + threadIdx.x; i < hi; i += 256) s += y[i];
    sh[threadIdx.x] = s;
    __syncthreads();
    for (int off = 128; off > 0; off >>= 1) {
        if (threadIdx.x < off) sh[threadIdx.x] += sh[threadIdx.x + off];
        __syncthreads();
    }
    if (threadIdx.x == 0) {
        float cnt = (float)(hi - lo);
        out[g] = sh[0] / fmaxf(cnt, 1.0f) + bh[0];
    }
}

// ------------------------- launch -------------------------
extern "C" void kernel_launch(void* const* d_in, const int* in_sizes, int n_in,
                              void* d_out, int out_size, void* d_ws, size_t ws_size,
                              hipStream_t stream) {
    const float* x    = (const float*)d_in[0];
    const int*   eidx = (const int*)d_in[1];
    const int*   batch= (const int*)d_in[2];
    const float* W1   = (const float*)d_in[3];
    const float* b1   = (const float*)d_in[4];
    const float* W2   = (const float*)d_in[5];
    const float* b2   = (const float*)d_in[6];
    const float* eps  = (const float*)d_in[7];
    const float* Wh   = (const float*)d_in[8];
    const float* bh   = (const float*)d_in[9];

    const int N = in_sizes[0] / H;   // 50000
    const int E = in_sizes[1] / 2;   // 800000
    const int L = in_sizes[7];       // 3
    const int* src  = eidx;
    const int* dstv = eidx + E;
    float* out = (float*)d_out;

    const int NB = (N + NPB - 1) / NPB;   // 196 (<= 256 required)

    char* w = (char*)d_ws;
    u16* B0 = (u16*)w; w += (size_t)N * H * sizeof(u16);
    u16* B1 = (u16*)w; w += (size_t)N * H * sizeof(u16);
    u16* packedW = (u16*)w; w += (size_t)6 * H * H * sizeof(u16);
    float* y    = (float*)w; w += (size_t)N * sizeof(float);
    int* offs   = (int*)w;   w += (size_t)(N + 1) * sizeof(int);
    int* bcnt   = (int*)w;   w += 256 * sizeof(int);
    int* bcursor= (int*)w;   w += 256 * sizeof(int);
    u32* stage  = (u32*)w;   w += (size_t)E * sizeof(u32);
    int* cols   = (int*)w;   w += (size_t)E * sizeof(int);

    // bcnt + bcursor are adjacent: one memset zeroes both
    hipMemsetAsync(bcnt, 0, 512 * sizeof(int), stream);

    // prep: convert | pack | hist in one launch
    const int n4 = N * H / 4;
    const int total = 6 * H * H;
    const int nConv = (n4 + 255) / 256;       // 6250
    const int nPack = (total + 255) / 256;    // 384
    prep_kernel<<<nConv + nPack + 256, 256, 0, stream>>>(x, B0, W1, W2, packedW,
                                                         dstv, bcnt, n4, total, E, NB,
                                                         nConv, nPack);

    // CSR build (bucket sort; scatter/build compute boffs in-block, bcursor is relative)
    scatter_kernel<<<(E + SCHUNK - 1) / SCHUNK, 256, 0, stream>>>(src, dstv, bcnt, bcursor,
                                                                  stage, E, NB);
    build_csr<<<NB, 256, 0, stream>>>(stage, bcnt, offs, cols, N, NB, E);

    const int numTiles = (N + 15) / 16;   // 3125 -> one block per tile
    u16* bufs[2] = { B0, B1 };
    int cur = 0;
    for (int l = 0; l < L; ++l) {
        int nxt = cur ^ 1;
        int last = (l == L - 1) ? 1 : 0;
        fused_layer<<<numTiles, 256, 0, stream>>>(bufs[cur], bufs[nxt], offs, cols,
                                                  packedW + (size_t)l * H * H,
                                                  packedW + (size_t)(3 + l) * H * H,
                                                  b1 + (size_t)l * H, b2 + (size_t)l * H,
                                                  eps, l, (l < L - 1) ? 1 : 0, last,
                                                  Wh, y, N);
        cur = nxt;
    }

    seg_out_kernel<<<NGRAPH, 256, 0, stream>>>(y, batch, bh, out, N);
}

// Round 14
// 235.686 us; speedup vs baseline: 1.3252x; 1.0413x over previous
//
#include <hip/hip_runtime.h>
#include <cstdint>

#define H 128
#define NGRAPH 256
#define ROWSTRIDE 68   // u32 per LDS tile row (64 data + 4 pad) -> 2-way max bank conflict
#define NPB 256        // nodes per bucket (bucket = dst >> 8); requires N <= 65536
#define CSR_CAP 6144   // LDS staging entries per bucket (mean ~4080, +32 sigma safe)
// [R11 lesson: NPB=128/SCHUNK=1024 "grid fix" regressed 263->312 µs. Scatter is
//  write-amplification-bound, not latency-bound: run length per (block,bucket) =
//  SCHUNK/NB must stay ~20 edges (80B). Keep SCHUNK=4096, NB=196.]
#define SCHUNK 4096

typedef __attribute__((ext_vector_type(8))) short short8;
typedef __attribute__((ext_vector_type(4))) float floatx4;

typedef unsigned short u16;
typedef unsigned int u32;

__device__ __forceinline__ u16 f2b(float f) {
    union { float f; u32 u; } v; v.f = f;
    u32 r = v.u + 0x7fffu + ((v.u >> 16) & 1u);
    return (u16)(r >> 16);
}
// bare u16 bf16 -> float (ONE shift)
__device__ __forceinline__ float b2f(u16 b) {
    union { u32 u; float f; } v; v.u = ((u32)b) << 16;
    return v.f;
}
// packed-pair helpers: take the full u32 holding two bf16
__device__ __forceinline__ float lo_f(u32 v) {
    union { u32 u; float f; } w; w.u = v << 16; return w.f;
}
__device__ __forceinline__ float hi_f(u32 v) {
    union { u32 u; float f; } w; w.u = v & 0xffff0000u; return w.f;
}

// ------------------------- prep: convert x->bf16 | pack W | bucket hist -------------------------
// [R13: merged 3 kernels into one block-role-dispatch launch to cut graph dispatch count]
__global__ __launch_bounds__(256) void prep_kernel(const float* __restrict__ x,
                                                   u16* __restrict__ xb,
                                                   const float* __restrict__ W1,
                                                   const float* __restrict__ W2,
                                                   u16* __restrict__ packed,
                                                   const int* __restrict__ dstv,
                                                   int* __restrict__ bcnt,
                                                   int n4, int total, int E, int NB,
                                                   int nConv, int nPack) {
    __shared__ int sh[256];
    const int t = threadIdx.x;
    const int b = blockIdx.x;
    if (b < nConv) {
        // convert
        int i = b * 256 + t;
        if (i < n4) {
            float4 v = *(const float4*)(x + (size_t)i * 4);
            u16 o[4] = { f2b(v.x), f2b(v.y), f2b(v.z), f2b(v.w) };
            *(uint2*)(xb + (size_t)i * 4) = *(uint2*)o;
        }
    } else if (b < nConv + nPack) {
        // pack W into MFMA B-fragment order:
        // packed[mat][((kc*8+nt)*64+lane)*8+j] = W[mat][k=kc*32+(lane>>4)*8+j][n=nt*16+(lane&15)]
        int idx = (b - nConv) * 256 + t;
        if (idx < total) {
            int mat = idx >> 14;
            int pos = idx & 16383;
            int j    = pos & 7;
            int lane = (pos >> 3) & 63;
            int nt   = (pos >> 9) & 7;
            int kc   = pos >> 12;
            int k = kc * 32 + (lane >> 4) * 8 + j;
            int n = nt * 16 + (lane & 15);
            const float* src = (mat < 3) ? (W1 + (size_t)mat * H * H)
                                         : (W2 + (size_t)(mat - 3) * H * H);
            packed[idx] = f2b(src[(size_t)k * H + n]);
        }
    } else {
        // bucket histogram (LDS-local, one global atomic per bucket per block)
        int bb = b - nConv - nPack;          // 0..255
        sh[t] = 0;
        __syncthreads();
        for (int e = bb * 256 + t; e < E; e += 256 * 256)
            atomicAdd(&sh[dstv[e] >> 8], 1);
        __syncthreads();
        if (t < NB && sh[t] > 0) atomicAdd(&bcnt[t], sh[t]);
    }
}

// ------------------------- scatter into bucket-contiguous staging -------------------------
// Computes boffs via in-block LDS scan of bcnt (196 entries); bcursor holds RELATIVE
// offsets (zero-initialized by the host memset). One global atomic per (block,bucket).
__global__ __launch_bounds__(256) void scatter_kernel(const int* __restrict__ src,
                                                      const int* __restrict__ dstv,
                                                      const int* __restrict__ bcnt,
                                                      int* __restrict__ bcursor,
                                                      u32* __restrict__ stage, int E, int NB) {
    __shared__ int lcnt[256];
    __shared__ int lbase[256];
    __shared__ int sA[256];
    __shared__ int sB[256];
    int t = threadIdx.x;
    // in-block exclusive scan of bcnt -> sB = boffs
    int v = (t < NB) ? bcnt[t] : 0;
    sA[t] = v;
    lcnt[t] = 0;
    __syncthreads();
    int* a = sA; int* bb2 = sB;
    for (int off = 1; off < 256; off <<= 1) {
        bb2[t] = (t >= off) ? (a[t] + a[t - off]) : a[t];
        __syncthreads();
        int* tmp = a; a = bb2; bb2 = tmp;
    }
    // after 8 iters a == sA (even swaps); write exclusive prefix into sB
    bb2[t] = a[t] - v;   // bb2 == sB
    __syncthreads();

    int base = blockIdx.x * SCHUNK;
    u32 pk[16];
    int bk[16];
#pragma unroll
    for (int i = 0; i < 16; ++i) {
        int idx = base + t + i * 256;
        bk[i] = -1;
        if (idx < E) {
            int s = src[idx];
            int d = dstv[idx];
            int b = d >> 8;
            pk[i] = (u32)s | ((u32)(d & 255) << 24);   // src < 2^24
            bk[i] = b;
            atomicAdd(&lcnt[b], 1);
        }
    }
    __syncthreads();
    if (t < NB && lcnt[t] > 0) lbase[t] = sB[t] + atomicAdd(&bcursor[t], lcnt[t]);
    __syncthreads();
    lcnt[t] = 0;
    __syncthreads();
#pragma unroll
    for (int i = 0; i < 16; ++i) {
        if (bk[i] >= 0) {
            int r = atomicAdd(&lcnt[bk[i]], 1);
            stage[(size_t)lbase[bk[i]] + r] = pk[i];
        }
    }
}

// ------------------------- build CSR from staged buckets -------------------------
// One block per bucket; computes its own lo/hi via in-block scan of bcnt. Per-node
// count -> LDS scan -> offs (coalesced) -> LDS col scatter -> linear write-out.
__global__ __launch_bounds__(256) void build_csr(const u32* __restrict__ stage,
                                                 const int* __restrict__ bcnt,
                                                 int* __restrict__ offs, int* __restrict__ cols,
                                                 int N, int NB, int E) {
    __shared__ int cnt[256];
    __shared__ int cur[256];
    __shared__ int sA[256];
    __shared__ int sB[256];
    __shared__ int colstage[CSR_CAP];
    int b = blockIdx.x;
    int t = threadIdx.x;
    // in-block inclusive scan of bcnt -> lo/hi for this bucket
    int v = (t < NB) ? bcnt[t] : 0;
    sA[t] = v;
    __syncthreads();
    int* a = sA; int* bb2 = sB;
    for (int off = 1; off < 256; off <<= 1) {
        bb2[t] = (t >= off) ? (a[t] + a[t - off]) : a[t];
        __syncthreads();
        int* tmp = a; a = bb2; bb2 = tmp;
    }
    int lo = (b == 0) ? 0 : a[b - 1];
    int hi = a[b];
    __syncthreads();          // sA/sB reused below
    int sz = hi - lo;
    int nlo = b * NPB;
    cnt[t] = 0;
    __syncthreads();
    for (int i = t; i < sz; i += 256) atomicAdd(&cnt[stage[(size_t)lo + i] >> 24], 1);
    __syncthreads();
    sA[t] = cnt[t];
    __syncthreads();
    a = sA; bb2 = sB;
    for (int off = 1; off < 256; off <<= 1) {
        bb2[t] = (t >= off) ? (a[t] + a[t - off]) : a[t];
        __syncthreads();
        int* tmp = a; a = bb2; bb2 = tmp;
    }
    int excl = a[t] - cnt[t];
    if (nlo + t < N) offs[nlo + t] = lo + excl;
    if (b == 0 && t == 0) offs[N] = E;
    cur[t] = excl;
    __syncthreads();
    if (sz <= CSR_CAP) {
        for (int i = t; i < sz; i += 256) {
            u32 pk = stage[(size_t)lo + i];
            int r = atomicAdd(&cur[pk >> 24], 1);
            colstage[r] = (int)(pk & 0xFFFFFFu);
        }
        __syncthreads();
        for (int i = t; i < sz; i += 256) cols[(size_t)lo + i] = colstage[i];
    } else {
        for (int i = t; i < sz; i += 256) {
            u32 pk = stage[(size_t)lo + i];
            int r = atomicAdd(&cur[pk >> 24], 1);
            cols[(size_t)lo + r] = (int)(pk & 0xFFFFFFu);
        }
    }
}

// ------------------------- fused GIN layer -------------------------
// [R14: 32-node tile / 512 threads — halves block count (1563) and thus per-block
//  weight-fragment traffic (200 -> 100 MB/layer L2-side) and barrier/epilogue overhead.
//  Gather per 16-lane group unchanged.]
// One block per 32-node tile: gather (CSR) -> LDS -> MFMA GEMM1(+bias,ReLU) -> LDS ->
// MFMA GEMM2(+bias,opt ReLU) -> store (or, last layer, fused dot with Wh -> y).
// 8 waves; wave w owns output col-tile nt=w for BOTH 16-row subtiles.
// [R8: wave-sequential gather regressed — MLP > exec-mask efficiency.]
// [R10: dword->dwordx4 neutral — gather is at the L2/L3 random-access plateau
//  (~5 TB/s effective); this dword version measured best (R9/R12: 258.5 µs).]
__global__ __launch_bounds__(512) void fused_layer(const u16* __restrict__ h,
                                                   u16* __restrict__ hout,
                                                   const int* __restrict__ offs,
                                                   const int* __restrict__ cols,
                                                   const u16* __restrict__ Wp1,
                                                   const u16* __restrict__ Wp2,
                                                   const float* __restrict__ bias1,
                                                   const float* __restrict__ bias2,
                                                   const float* __restrict__ eps, int layer,
                                                   int relu2, int lastLayer,
                                                   const float* __restrict__ Wh,
                                                   float* __restrict__ y, int N) {
    __shared__ u32 ldsA[32 * ROWSTRIDE];
    __shared__ u32 ldsB[32 * ROWSTRIDE];
    __shared__ float dacc[32];

    const int tid = threadIdx.x;
    const int wave = tid >> 6;        // 0..7
    const int lane = tid & 63;
    const int m = lane & 15;
    const int quad = lane >> 4;
    const int nt = wave;              // col-tile 0..7
    const int row0 = blockIdx.x * 32;

    const float scale = 1.0f + eps[layer];
    const u32* __restrict__ hp = (const u32*)h;

    // ---- gather: group-parallel; lane covers 4 u32 (8 feats) of its group's node ----
    {
        const int nid = wave * 4 + quad;       // 0..31
        const int node = row0 + nid;
        float a[8];
#pragma unroll
        for (int i = 0; i < 8; ++i) a[i] = 0.f;
        if (node < N) {
#pragma unroll
            for (int i = 0; i < 4; ++i) {
                u32 v = hp[(size_t)node * 64 + m + 16 * i];
                a[2 * i]     = scale * lo_f(v);
                a[2 * i + 1] = scale * hi_f(v);
            }
            int beg = offs[node], end = offs[node + 1];
            int j = beg;
            for (; j + 4 <= end; j += 4) {
                int c0 = cols[j], c1 = cols[j + 1], c2 = cols[j + 2], c3 = cols[j + 3];
                u32 v0[4], v1[4], v2[4], v3[4];
#pragma unroll
                for (int i = 0; i < 4; ++i) v0[i] = hp[(size_t)c0 * 64 + m + 16 * i];
#pragma unroll
                for (int i = 0; i < 4; ++i) v1[i] = hp[(size_t)c1 * 64 + m + 16 * i];
#pragma unroll
                for (int i = 0; i < 4; ++i) v2[i] = hp[(size_t)c2 * 64 + m + 16 * i];
#pragma unroll
                for (int i = 0; i < 4; ++i) v3[i] = hp[(size_t)c3 * 64 + m + 16 * i];
#pragma unroll
                for (int i = 0; i < 4; ++i) {
                    a[2 * i]     += (lo_f(v0[i]) + lo_f(v1[i])) + (lo_f(v2[i]) + lo_f(v3[i]));
                    a[2 * i + 1] += (hi_f(v0[i]) + hi_f(v1[i])) + (hi_f(v2[i]) + hi_f(v3[i]));
                }
            }
            for (; j < end; ++j) {
                int c0 = cols[j];
#pragma unroll
                for (int i = 0; i < 4; ++i) {
                    u32 v = hp[(size_t)c0 * 64 + m + 16 * i];
                    a[2 * i]     += lo_f(v);
                    a[2 * i + 1] += hi_f(v);
                }
            }
        }
#pragma unroll
        for (int i = 0; i < 4; ++i) {
            u16 p[2] = { f2b(a[2 * i]), f2b(a[2 * i + 1]) };
            ldsA[nid * ROWSTRIDE + m + 16 * i] = *(u32*)p;
        }
    }

    // B fragments (loaded in the gather's latency shadow): ONE col-tile per wave
    short8 B1f[4], B2f[4];
#pragma unroll
    for (int kc = 0; kc < 4; ++kc) {
        B1f[kc] = *(const short8*)(Wp1 + ((size_t)(kc * 8 + nt) * 64 + lane) * 8);
        B2f[kc] = *(const short8*)(Wp2 + ((size_t)(kc * 8 + nt) * 64 + lane) * 8);
    }
    const int cg = nt * 16 + m;
    const float b1v = bias1[cg];
    const float b2v = bias2[cg];
    if (tid < 32) dacc[tid] = 0.f;
    __syncthreads();

    // ---- GEMM1: z1 = relu(z0 @ W1 + b1), both 16-row subtiles ----
    {
        floatx4 acc0 = {0.f, 0.f, 0.f, 0.f};   // rows 0..15
        floatx4 acc1 = {0.f, 0.f, 0.f, 0.f};   // rows 16..31
#pragma unroll
        for (int kc = 0; kc < 4; ++kc) {
            short8 a0 = *(const short8*)(&ldsA[(0 + m) * ROWSTRIDE + kc * 16 + quad * 4]);
            short8 a1 = *(const short8*)(&ldsA[(16 + m) * ROWSTRIDE + kc * 16 + quad * 4]);
            acc0 = __builtin_amdgcn_mfma_f32_16x16x32_bf16(a0, B1f[kc], acc0, 0, 0, 0);
            acc1 = __builtin_amdgcn_mfma_f32_16x16x32_bf16(a1, B1f[kc], acc1, 0, 0, 0);
        }
        u16* lb = (u16*)ldsB;
#pragma unroll
        for (int i = 0; i < 4; ++i) {
            int rr = quad * 4 + i;
            lb[rr * (ROWSTRIDE * 2) + cg]        = f2b(fmaxf(acc0[i] + b1v, 0.f));
            lb[(16 + rr) * (ROWSTRIDE * 2) + cg] = f2b(fmaxf(acc1[i] + b1v, 0.f));
        }
    }
    __syncthreads();

    // ---- GEMM2: z2 = (relu?)(z1 @ W2 + b2) ----
    {
        floatx4 acc0 = {0.f, 0.f, 0.f, 0.f};
        floatx4 acc1 = {0.f, 0.f, 0.f, 0.f};
#pragma unroll
        for (int kc = 0; kc < 4; ++kc) {
            short8 a0 = *(const short8*)(&ldsB[(0 + m) * ROWSTRIDE + kc * 16 + quad * 4]);
            short8 a1 = *(const short8*)(&ldsB[(16 + m) * ROWSTRIDE + kc * 16 + quad * 4]);
            acc0 = __builtin_amdgcn_mfma_f32_16x16x32_bf16(a0, B2f[kc], acc0, 0, 0, 0);
            acc1 = __builtin_amdgcn_mfma_f32_16x16x32_bf16(a1, B2f[kc], acc1, 0, 0, 0);
        }

        if (!lastLayer) {
            u16* la = (u16*)ldsA;
#pragma unroll
            for (int i = 0; i < 4; ++i) {
                int rr = quad * 4 + i;
                float v0 = acc0[i] + b2v;
                float v1 = acc1[i] + b2v;
                if (relu2) { v0 = fmaxf(v0, 0.f); v1 = fmaxf(v1, 0.f); }
                la[rr * (ROWSTRIDE * 2) + cg]        = f2b(v0);
                la[(16 + rr) * (ROWSTRIDE * 2) + cg] = f2b(v1);
            }
            __syncthreads();
            // coalesced store: 512 threads x 16B = 32 rows x 256B
            int rr = tid >> 4;          // 0..31
            int s  = tid & 15;
            int grow = row0 + rr;
            if (grow < N) {
                uint4 v = *(uint4*)(&ldsA[rr * ROWSTRIDE + s * 4]);
                *(uint4*)(hout + (size_t)grow * H + s * 8) = v;
            }
        } else {
            // fused head: y[row] = sum_c bf16(z2[row][c]) * Wh[c]
            const float wh = Wh[cg];
            float p0[4], p1[4];
#pragma unroll
            for (int i = 0; i < 4; ++i) {
                p0[i] = b2f(f2b(acc0[i] + b2v)) * wh;
                p1[i] = b2f(f2b(acc1[i] + b2v)) * wh;
            }
            // reduce across the 16 lanes of each quad group (xor masks < 16 stay in-group)
#pragma unroll
            for (int off = 1; off < 16; off <<= 1)
#pragma unroll
                for (int i = 0; i < 4; ++i) {
                    p0[i] += __shfl_xor(p0[i], off, 64);
                    p1[i] += __shfl_xor(p1[i], off, 64);
                }
            if (m == 0) {
#pragma unroll
                for (int i = 0; i < 4; ++i) {
                    atomicAdd(&dacc[quad * 4 + i], p0[i]);
                    atomicAdd(&dacc[16 + quad * 4 + i], p1[i]);
                }
            }
            __syncthreads();
            if (tid < 32 && row0 + tid < N) y[row0 + tid] = dacc[tid];
        }
    }
}

// ------------------------- per-graph mean via binary search on sorted batch -------------------------
__device__ __forceinline__ int lbound(const int* __restrict__ a, int n, int v) {
    int lo = 0, hi = n;
    while (lo < hi) { int mid = (lo + hi) >> 1; if (a[mid] < v) lo = mid + 1; else hi = mid; }
    return lo;
}

__global__ void seg_out_kernel(const float* __restrict__ y, const int* __restrict__ batch,
                               const float* __restrict__ bh, float* __restrict__ out, int N) {
    __shared__ float sh[256];
    int g = blockIdx.x;
    int lo = lbound(batch, N, g);
    int hi = lbound(batch, N, g + 1);
    float s = 0.f;
    for (int i = lo + threadIdx.x; i < hi; i += 256) s += y[i];
    sh[threadIdx.x] = s;
    __syncthreads();
    for (int off = 128; off > 0; off >>= 1) {
        if (threadIdx.x < off) sh[threadIdx.x] += sh[threadIdx.x + off];
        __syncthreads();
    }
    if (threadIdx.x == 0) {
        float cnt = (float)(hi - lo);
        out[g] = sh[0] / fmaxf(cnt, 1.0f) + bh[0];
    }
}

// ------------------------- launch -------------------------
extern "C" void kernel_launch(void* const* d_in, const int* in_sizes, int n_in,
                              void* d_out, int out_size, void* d_ws, size_t ws_size,
                              hipStream_t stream) {
    const float* x    = (const float*)d_in[0];
    const int*   eidx = (const int*)d_in[1];
    const int*   batch= (const int*)d_in[2];
    const float* W1   = (const float*)d_in[3];
    const float* b1   = (const float*)d_in[4];
    const float* W2   = (const float*)d_in[5];
    const float* b2   = (const float*)d_in[6];
    const float* eps  = (const float*)d_in[7];
    const float* Wh   = (const float*)d_in[8];
    const float* bh   = (const float*)d_in[9];

    const int N = in_sizes[0] / H;   // 50000
    const int E = in_sizes[1] / 2;   // 800000
    const int L = in_sizes[7];       // 3
    const int* src  = eidx;
    const int* dstv = eidx + E;
    float* out = (float*)d_out;

    const int NB = (N + NPB - 1) / NPB;   // 196 (<= 256 required)

    char* w = (char*)d_ws;
    u16* B0 = (u16*)w; w += (size_t)N * H * sizeof(u16);
    u16* B1 = (u16*)w; w += (size_t)N * H * sizeof(u16);
    u16* packedW = (u16*)w; w += (size_t)6 * H * H * sizeof(u16);
    float* y    = (float*)w; w += (size_t)N * sizeof(float);
    int* offs   = (int*)w;   w += (size_t)(N + 1) * sizeof(int);
    int* bcnt   = (int*)w;   w += 256 * sizeof(int);
    int* bcursor= (int*)w;   w += 256 * sizeof(int);
    u32* stage  = (u32*)w;   w += (size_t)E * sizeof(u32);
    int* cols   = (int*)w;   w += (size_t)E * sizeof(int);

    // bcnt + bcursor are adjacent: one memset zeroes both
    hipMemsetAsync(bcnt, 0, 512 * sizeof(int), stream);

    // prep: convert | pack | hist in one launch
    const int n4 = N * H / 4;
    const int total = 6 * H * H;
    const int nConv = (n4 + 255) / 256;       // 6250
    const int nPack = (total + 255) / 256;    // 384
    prep_kernel<<<nConv + nPack + 256, 256, 0, stream>>>(x, B0, W1, W2, packedW,
                                                         dstv, bcnt, n4, total, E, NB,
                                                         nConv, nPack);

    // CSR build (bucket sort; scatter/build compute boffs in-block, bcursor is relative)
    scatter_kernel<<<(E + SCHUNK - 1) / SCHUNK, 256, 0, stream>>>(src, dstv, bcnt, bcursor,
                                                                  stage, E, NB);
    build_csr<<<NB, 256, 0, stream>>>(stage, bcnt, offs, cols, N, NB, E);

    const int numTiles = (N + 31) / 32;   // 1563 -> one block per 32-node tile
    u16* bufs[2] = { B0, B1 };
    int cur = 0;
    for (int l = 0; l < L; ++l) {
        int nxt = cur ^ 1;
        int last = (l == L - 1) ? 1 : 0;
        fused_layer<<<numTiles, 512, 0, stream>>>(bufs[cur], bufs[nxt], offs, cols,
                                                  packedW + (size_t)l * H * H,
                                                  packedW + (size_t)(3 + l) * H * H,
                                                  b1 + (size_t)l * H, b2 + (size_t)l * H,
                                                  eps, l, (l < L - 1) ? 1 : 0, last,
                                                  Wh, y, N);
        cur = nxt;
    }

    seg_out_kernel<<<NGRAPH, 256, 0, stream>>>(y, batch, bh, out, N);
}